// Round 1
// baseline (1791.913 us; speedup 1.0000x reference)
//
#include <hip/hip_runtime.h>
#include <hip/hip_bf16.h>

#define B_    16
#define N_    65536
#define CI    256
#define CO    256
#define RANK_ 10
#define TN    128   // n-rows per block

typedef __bf16 bf16x8 __attribute__((ext_vector_type(8)));
typedef float  f32x16 __attribute__((ext_vector_type(16)));

__device__ __forceinline__ unsigned short f2bf_rne(float f) {
    union { float f; unsigned u; } v; v.f = f;
    unsigned u = v.u;
    return (unsigned short)((u + 0x7FFFu + ((u >> 16) & 1u)) >> 16);
}
__device__ __forceinline__ float bf2f(unsigned short h) {
    union { unsigned u; float f; } v; v.u = ((unsigned)h) << 16;
    return v.f;
}

// ---------------------------------------------------------------------------
// Kernel 1: W[b,o,i] = weight[o,i] * (sigmoid((left@right)/sqrt(rank)) + 0.5)
// split into Wh = bf16(W), Wl = bf16(W - Wh), stored in MFMA-B-fragment order:
//   wfrag[b][ot(8)][kt(16)][hl(2)][lane(64)][e(8)]
//   where for v_mfma_f32_32x32x16_bf16:  o = ot*32 + (lane&31),
//                                        k = kt*16 + (lane>>5)*8 + e
// so the main kernel's B-frag load is a fully coalesced per-lane dwordx4.
// ---------------------------------------------------------------------------
__global__ void fmm_prep(const float* __restrict__ freq,
                         const float* __restrict__ weight,
                         unsigned short* __restrict__ wfrag) {
    int b = blockIdx.x >> 8;
    int o = blockIdx.x & 255;
    int i = threadIdx.x;
    const float* fb = freq + (size_t)b * (RANK_ * (CI + CO));
    float m = 0.f;
#pragma unroll
    for (int r = 0; r < RANK_; ++r)
        m += fb[o * RANK_ + r] * fb[CO * RANK_ + r * CI + i];
    m *= 0.31622776601683794f;                 // 1/sqrt(rank)
    float sig = 1.f / (1.f + expf(-m));
    float wv  = weight[o * CI + i] * (sig + 0.5f);   // (sigmoid-0.5)+1
    unsigned short hi = f2bf_rne(wv);
    unsigned short lo = f2bf_rne(wv - bf2f(hi));
    int ot = o >> 5, kt = i >> 4, half = (i >> 3) & 1, e = i & 7;
    int L  = (o & 31) | (half << 5);
    size_t idx = (((size_t)((b << 3) | ot) * 16 + kt) * 2) * 512 + L * 8 + e;
    wfrag[idx]       = hi;   // hl = 0
    wfrag[idx + 512] = lo;   // hl = 1
}

// ---------------------------------------------------------------------------
// Kernel 2: per block: 128 n-rows x all 256 o, K=256 in two 128-chunks.
// 256 threads = 4 waves, wave w owns o in [64w, 64w+64) -> 4x2 32x32 MFMA
// tiles, W hi/lo fragments streamed from L2 (prefetched 1 k-step ahead).
// x staged f32->bf16 into LDS (stride 136 ushorts: 16B-aligned rows).
// ---------------------------------------------------------------------------
__global__ __launch_bounds__(256, 2) void fmm_main(
    const float* __restrict__ x, const unsigned short* __restrict__ wfrag,
    const float* __restrict__ ps, float* __restrict__ out) {
    __shared__ unsigned short xs[TN * 136];   // 34,816 B

    const int tid  = threadIdx.x;
    const int lane = tid & 63;
    const int w    = tid >> 6;
    const int b    = blockIdx.y;
    const int n0   = blockIdx.x * TN;

    const float4* xsrc = (const float4*)(x + ((size_t)b * N_ + n0) * CI);

    const int arow  = lane & 31;
    const int ahalf = lane >> 5;

    // wave's W base: ot = w*2 (+j), per-(b,ot) chunk = 16 kt * 2 hl * 512 = 16384
    const unsigned short* wp0 =
        wfrag + (size_t)((b << 3) | (w << 1)) * 16384 + lane * 8;

    f32x16 acc[4][2];
#pragma unroll
    for (int i = 0; i < 4; ++i)
#pragma unroll
        for (int j = 0; j < 2; ++j)
#pragma unroll
            for (int r = 0; r < 16; ++r) acc[i][j][r] = 0.f;

    uint4 wc[4], wn[4];
#pragma unroll
    for (int q = 0; q < 4; ++q)   // kt = 0 frags: q = j*2 + hl
        wc[q] = *(const uint4*)(wp0 + (q >> 1) * 16384 + (q & 1) * 512);

    for (int ko = 0; ko < 2; ++ko) {
        if (ko) __syncthreads();   // all waves done reading previous chunk
        // ---- stage x[n0:n0+128][ko*128 : ko*128+128] as bf16 into LDS ----
        float4 v[16];
#pragma unroll
        for (int it = 0; it < 16; ++it) {
            int idx = tid + it * 256;           // 0..4095
            int r = idx >> 5, c4 = idx & 31;
            v[it] = xsrc[r * 64 + ko * 32 + c4];
        }
#pragma unroll
        for (int it = 0; it < 16; ++it) {
            int idx = tid + it * 256;
            int r = idx >> 5, c4 = idx & 31;
            ushort4 pk = make_ushort4(f2bf_rne(v[it].x), f2bf_rne(v[it].y),
                                      f2bf_rne(v[it].z), f2bf_rne(v[it].w));
            *(ushort4*)(&xs[r * 136 + c4 * 4]) = pk;
        }
        __syncthreads();

        // ---- K inner loop: 8 steps of k16 per chunk ----
#pragma unroll
        for (int kt2 = 0; kt2 < 8; ++kt2) {
            const int kt = ko * 8 + kt2;
            bf16x8 a[4];
#pragma unroll
            for (int i = 0; i < 4; ++i)
                a[i] = *(const bf16x8*)(&xs[(i * 32 + arow) * 136 +
                                            ahalf * 8 + kt2 * 16]);
            if (kt < 15) {
#pragma unroll
                for (int q = 0; q < 4; ++q)
                    wn[q] = *(const uint4*)(wp0 + (q >> 1) * 16384 +
                                            (kt + 1) * 1024 + (q & 1) * 512);
            }
#pragma unroll
            for (int i = 0; i < 4; ++i) {
#pragma unroll
                for (int j = 0; j < 2; ++j) {
                    acc[i][j] = __builtin_amdgcn_mfma_f32_32x32x16_bf16(
                        a[i], __builtin_bit_cast(bf16x8, wc[j * 2 + 0]),
                        acc[i][j], 0, 0, 0);
                    acc[i][j] = __builtin_amdgcn_mfma_f32_32x32x16_bf16(
                        a[i], __builtin_bit_cast(bf16x8, wc[j * 2 + 1]),
                        acc[i][j], 0, 0, 0);
                }
            }
#pragma unroll
            for (int q = 0; q < 4; ++q) wc[q] = wn[q];
        }
    }

    // ---- epilogue: out = sin(fs*acc + ph) ----
    // C/D layout (32x32, HW-verified): col = lane&31, row = (r&3)+8*(r>>2)+4*(lane>>5)
    const float* psb = ps + (size_t)b * (2 * CO);
#pragma unroll
    for (int j = 0; j < 2; ++j) {
        int o = (w << 6) | (j * 32 + arow);
        float fs = psb[o];
        float ph = (psb[CO + o] - 30.f) * (1.f / 15.f);
#pragma unroll
        for (int i = 0; i < 4; ++i) {
            int nbase = n0 + i * 32 + (ahalf << 2);
#pragma unroll
            for (int r = 0; r < 16; ++r) {
                int nrow = nbase + (r & 3) + ((r >> 2) << 3);
                out[((size_t)b * N_ + nrow) * CO + o] =
                    __sinf(fs * acc[i][j][r] + ph);
            }
        }
    }
}

extern "C" void kernel_launch(void* const* d_in, const int* in_sizes, int n_in,
                              void* d_out, int out_size, void* d_ws, size_t ws_size,
                              hipStream_t stream) {
    (void)in_sizes; (void)n_in; (void)out_size; (void)ws_size;
    const float* x      = (const float*)d_in[0];
    const float* freq   = (const float*)d_in[1];
    const float* ps     = (const float*)d_in[2];
    const float* weight = (const float*)d_in[3];
    float* out = (float*)d_out;
    unsigned short* wfrag = (unsigned short*)d_ws;   // 4 MiB

    fmm_prep<<<dim3(B_ * CO), CI, 0, stream>>>(freq, weight, wfrag);
    fmm_main<<<dim3(N_ / TN, B_), 256, 0, stream>>>(x, wfrag, ps, out);
}